// Round 15
// baseline (158.783 us; speedup 1.0000x reference)
//
#include <hip/hip_runtime.h>
#include <math.h>

// Problem constants (match reference)
#define BB 8
#define AA 512
#define NBH 64
#define FF 128
#define GG 50
#define CUTOFF 5.0f

typedef __attribute__((ext_vector_type(8)))  short bf16x8;   // 8 bf16 = 4 VGPRs
typedef __attribute__((ext_vector_type(4)))  float f32x4;    // 16x16 MFMA C/D
typedef __attribute__((ext_vector_type(16))) float f32x16;   // 32x32 MFMA C/D

// Packed weight sizes (bf16 elems)
#define WKV_ELEMS (4*8*64*8)   // 16384 : Wk/Wv, 16-col B-frag layout, K=128 (4 steps of 32)
#define WQO_ELEMS (8*4*64*8)   // 16384 : Wq/Wo, 16-col B-frag layout, K=128 (4 steps of 32)
#define WF_ELEMS  (4*4*64*8)   // 8192  : W_filt, 32-col layout, K=64 pad; row 50 = b_filt
#define XB_ELEMS  (BB*AA*FF)   // 524288: x pre-converted to bf16

// RNE (prep only — off critical path)
__device__ __forceinline__ short f2bf(float f) {
    union { float f; unsigned u; } v; v.f = f;
    unsigned r = v.u + 0x7fffu + ((v.u >> 16) & 1u);
    return (short)(r >> 16);
}
// fast round-half-up (2 VALU)
__device__ __forceinline__ short f2bf_fast(float f) {
    return (short)((__float_as_uint(f) + 0x8000u) >> 16);
}
// pack 2 floats -> 2 bf16 in one dword: 2 adds + 1 v_perm
__device__ __forceinline__ unsigned int pk2bf(float a, float b) {
    unsigned int ua = __float_as_uint(a) + 0x8000u;
    unsigned int ub = __float_as_uint(b) + 0x8000u;
    return __builtin_amdgcn_perm(ub, ua, 0x07060302u);
}
// Load 8 consecutive floats (8B-aligned) -> bf16x8 A-fragment (packed cvt).
// Works for LDS-resident sources too (generic pointer -> ds_read_b64).
__device__ __forceinline__ bf16x8 ld_f8_bfpk(const float* p) {
    const float2* p2 = (const float2*)p;
    float2 a = p2[0], b = p2[1], c = p2[2], d = p2[3];
    union { unsigned int u[4]; bf16x8 v; } r;
    r.u[0] = pk2bf(a.x, a.y);
    r.u[1] = pk2bf(b.x, b.y);
    r.u[2] = pk2bf(c.x, c.y);
    r.u[3] = pk2bf(d.x, d.y);
    return r.v;
}

// Sum over the 16-lane DPP row (VALU pipe). All 16 lanes get the sum.
__device__ __forceinline__ float row16_sum(float x) {
    int t;
    t = __builtin_amdgcn_update_dpp(0, __float_as_int(x), 0x128, 0xf, 0xf, true); x += __int_as_float(t); // row_ror:8
    t = __builtin_amdgcn_update_dpp(0, __float_as_int(x), 0x124, 0xf, 0xf, true); x += __int_as_float(t); // row_ror:4
    t = __builtin_amdgcn_update_dpp(0, __float_as_int(x), 0x122, 0xf, 0xf, true); x += __int_as_float(t); // row_ror:2
    t = __builtin_amdgcn_update_dpp(0, __float_as_int(x), 0x121, 0xf, 0xf, true); x += __int_as_float(t); // row_ror:1
    return x;
}

// ---------------- prep: pack weights into MFMA B-fragment order + x -> bf16 ---------
// 16-col layout (Wk/Wv/Wq/Wo): dst[((c*4+s)*64+l)*8+j] = W[32s + (l>>4)*8 + j][16c + (l&15)]
// 32-col layout (Wf):          dst[((w*S+s)*64+l)*8+j] = W[16s + (l>>5)*8 + j][32w + (l&31)]
// Wf K-pad rows 50..63: row 50 carries b_filt (A supplies 1.0 there), 51..63 zero.
__global__ void prep_kernel(const float* __restrict__ Wk,
                            const float* __restrict__ Wv,
                            const float* __restrict__ Wq,
                            const float* __restrict__ Wo,
                            const float* __restrict__ Wf,
                            const float* __restrict__ b_filt,
                            const float* __restrict__ x,
                            short* __restrict__ ws)
{
    int gid = blockIdx.x * blockDim.x + threadIdx.x;
    if (gid < 2 * WKV_ELEMS + 2 * WQO_ELEMS) {
        const float* src = (gid < WKV_ELEMS) ? Wk :
                           (gid < 2 * WKV_ELEMS) ? Wv :
                           (gid < 2 * WKV_ELEMS + WQO_ELEMS) ? Wq : Wo;
        int idx = gid & (WKV_ELEMS - 1);   // all four regions are 16384
        int j = idx & 7, l = (idx >> 3) & 63, rest = idx >> 9;
        int s = rest & 3, c = rest >> 2;
        int k = 32 * s + ((l >> 4) << 3) + j;
        int n = 16 * c + (l & 15);
        ws[gid] = f2bf(src[k * FF + n]);
    } else if (gid < 2 * WKV_ELEMS + 2 * WQO_ELEMS + WF_ELEMS) {
        int idx = gid - 2 * WKV_ELEMS - 2 * WQO_ELEMS;
        int j = idx & 7, l = (idx >> 3) & 63, rest = idx >> 9;
        int s = rest & 3, w = rest >> 2;
        int k = 16 * s + ((l >> 5) << 3) + j;
        int n = 32 * w + (l & 31);
        float v = (k < GG) ? Wf[k * FF + n] : (k == GG ? b_filt[n] : 0.0f);
        ws[gid] = f2bf(v);
    } else {
        int idx = gid - 2 * WKV_ELEMS - 2 * WQO_ELEMS - WF_ELEMS;
        ws[gid] = f2bf(x[idx]);            // xB: straight layout, (b*AA+a)*FF + col
    }
}

// ---------------- main: one block per atom, 8 waves, 3 barriers ----------------
// R31 = R28 (passing, main 53.5us) with the wave→work map split 2x finer:
// 512 threads, 8 waves, ONE atom per block (NOT R20's failed 2-atom pairing —
// that doubled LDS and coupled unrelated atoms; here all 8 waves serve the
// same atom, which already required barriers). WHY: F_s staging confirmed the
// exposed-latency model again (61->53.5, predicted 52-56). Remaining profile:
// pipe-busy ~65% (VALU 46.5 + MFMA 18.8), ~35% all-wave stall; T_block ~24k
// cy vs ~5k critical path with only 4 waves covering it. Halving per-wave
// serial work and doubling waves/block doubles the TLP covering the same
// latency chain at the SAME LDS footprint. Per-wave MFMA 40->20.
// Map: wave w (0..7): phase 1b computes n-group nw=w>>2 (rows 32nw..+31) x
// col-group cw=w&3 (cols 32cw..+31) — one 32x32 MFMA chain (was two); phases
// 1a/2/3: one head-tile cg=w (16 cols) each (was two). All loop bodies,
// fragment layouts, swizzles VERBATIM R28; only index constants remapped.
// launch_bounds(512,4): identical 128-reg cap as the proven (256,4).
// History: R28 f_ij->F_s entry staging (+8us). R27 regressed (reverted).
// R24 ct-outer interchange failed correctness — bodies stay verbatim. NT
// loads (R23) regressed. R19 X_s in-place + source-side chunk-XOR swizzle
// (chunk ^= n&7), LDS dest linear (gl_lds HW). Max-free softmax; final 1/sum.
__global__ __launch_bounds__(512, 4)
void tdt_main(const float* __restrict__ x,
              const float* __restrict__ r_ij,
              const float* __restrict__ f_ij,
              const float* __restrict__ bo,
              const int*   __restrict__ neighbors,
              const int*   __restrict__ nmask,
              const short* __restrict__ WkB,
              const short* __restrict__ WvB,
              const short* __restrict__ WqB,
              const short* __restrict__ WoB,
              const short* __restrict__ WfB,
              const short* __restrict__ xB,
              float* __restrict__ out)
{
    const int ba   = blockIdx.x;          // 0..4095
    const int b    = ba >> 9;
    const int tid  = threadIdx.x;
    const int lane = tid & 63;
    const int w    = tid >> 6;            // wave 0..7
    const int cw   = w & 3;               // 1b col-group
    const int nw   = w >> 2;              // 1b n-group
    const int l15  = lane & 15;
    const int quad = lane >> 4;
    const int l31  = lane & 31;
    const int khalf = (lane >> 5) << 3;   // 0 or 8
    const int w5_4  = (lane >> 5) * 4;

    __shared__ short X_s[NBH * FF];       // gathered x rows, then (in-place) M (16 KB)
    __shared__ __attribute__((aligned(16))) float F_s[NBH * GG];  // f_ij slab (12.8 KB)
    __shared__ short msg_bf[FF];
    __shared__ float C_s[NBH];            // cosine cutoff per neighbor

    const float* xrow = x + (size_t)ba * FF;                       // residual (fp32)
    const unsigned short* xbu = (const unsigned short*)xB + (size_t)b * AA * FF;
    const size_t bao = (size_t)ba;

    // ---------------- entry A: stage f_ij slab -> F_s (async, 16B/lane) -------------
    // Slab = 800 16B-chunks. j=0: waves 0..7 cover chunks 0..511; j=1: waves
    // 0..3 cover 512..767; wave 4 tail covers 736..799 (736..767 overlap with
    // wave3/j1 writes identical bytes — idempotent). Waves 5..7 idle here.
    {
        const float* fsrc = f_ij + bao * (size_t)(NBH * GG);
        {
            int cbase = w * 64;
            __builtin_amdgcn_global_load_lds(
                (const __attribute__((address_space(1))) void*)(fsrc + (size_t)(cbase + lane) * 4),
                (__attribute__((address_space(3))) void*)&F_s[cbase * 4],
                16, 0, 0);
        }
        if (w < 4) {
            int cbase = (8 + w) * 64;
            __builtin_amdgcn_global_load_lds(
                (const __attribute__((address_space(1))) void*)(fsrc + (size_t)(cbase + lane) * 4),
                (__attribute__((address_space(3))) void*)&F_s[cbase * 4],
                16, 0, 0);
        } else if (w == 4) {
            __builtin_amdgcn_global_load_lds(
                (const __attribute__((address_space(1))) void*)(fsrc + (size_t)(736 + lane) * 4),
                (__attribute__((address_space(3))) void*)&F_s[736 * 4],
                16, 0, 0);
        }
    }

    // ---------------- entry B: issue neighbor-row gather into X_s (async, 16B/lane) -
    // Wave w stages rows [8w, 8w+8): iteration j covers rows 8w+4j..+3.
    // Lane l writes physical chunk (l&15) of row 8w+4j+(l>>4) (HW: uniform base +
    // lane*16B, linear). SOURCE chunk is (l&15)^(row&7) — so physical chunk jj of
    // row n holds global chunk jj^(n&7): the 16B-chunk XOR swizzle lives in the
    // global address, LDS dest stays linear (global_load_lds requirement).
    {
#pragma unroll
        for (int j = 0; j < 2; ++j) {
            int row = 8 * w + 4 * j + (lane >> 4);
            int nbn = neighbors[bao * NBH + row];
            int kk  = (lane & 15) ^ (row & 7);
            const unsigned short* src = xbu + (size_t)nbn * FF + (size_t)(kk * 8);
            __builtin_amdgcn_global_load_lds(
                (const __attribute__((address_space(1))) void*)src,
                (__attribute__((address_space(3))) void*)&X_s[(8 * w + 4 * j) * FF],
                16, 0, 0);
        }
    }

    // cutoff envelope -> C_s (wave 0 only; published by the phase-1a barrier)
    if (w == 0) {
        float r = r_ij[bao * NBH + lane];
        float c = 0.5f * (__cosf((float)M_PI * r * (1.0f / CUTOFF)) + 1.0f);
        C_s[lane] = (r < CUTOFF) ? c : 0.0f;
    }
    unsigned long long mask64 = __ballot(nmask[bao * NBH + lane] != 0);

    // ---------------- phase 1a: q via 16x16x32 MFMA (broadcast-A from xB) -----------
    // qs = 0.25 * q[16w + l15] — wave w owns head-tile cg = w.
    float qs;
    {
        const short* xbrow = &xB[(size_t)ba * FF];
        bf16x8 xa[4];
#pragma unroll
        for (int s = 0; s < 4; ++s)
            xa[s] = *(const bf16x8*)&xbrow[32 * s + quad * 8];     // raw 16B, no cvt
        f32x4 z = {0.f, 0.f, 0.f, 0.f};
#pragma unroll
        for (int s = 0; s < 4; ++s) {
            bf16x8 bq = *(const bf16x8*)&WqB[((w * 4 + s) * 64 + lane) * 8];
            z = __builtin_amdgcn_mfma_f32_16x16x32_bf16(xa[s], bq, z, 0, 0, 0);
        }
        qs = z[0] * 0.25f;                                         // fold 1/sqrt(DH)
    }
    __syncthreads();   // X_s + F_s + C_s ready (syncthreads drains vmcnt incl. gl_lds)

    // ---------------- phase 1b: filter 32x32x16 MFMA (A from LDS F_s) ---------------
    // Wave w: rows 32nw..+31 (A from F_s), cols 32cw..+31 (B frags). ONE chain.
    {
        const float* fm = F_s + (size_t)(32 * nw + l31) * GG;
        const int c_hi = 4 * cw + (l31 >> 3);  // c>>3 of this lane's column
        const int c_lo = l31 & 7;              // c&7
        f32x16 wacc;
#pragma unroll
        for (int r = 0; r < 16; ++r) wacc[r] = 0.0f;
#pragma unroll
        for (int s = 0; s < 4; ++s) {
            bf16x8 bfw = *(const bf16x8*)&WfB[((cw * 4 + s) * 64 + lane) * 8];
            bf16x8 fa;
            if (s < 3) {
                fa = ld_f8_bfpk(fm + 16 * s + khalf);
            } else {
                // k = 48 + khalf + j; k<50 real data, k==50 bias row (A=1.0)
#pragma unroll
                for (int jj = 0; jj < 8; ++jj) fa[jj] = 0;
                if (lane < 32) {
                    fa[0] = f2bf_fast(fm[48]);
                    fa[1] = f2bf_fast(fm[49]);
                    fa[2] = (short)0x3F80;   // 1.0bf16 -> adds b_filt row
                }
            }
            wacc = __builtin_amdgcn_mfma_f32_32x32x16_bf16(fa, bfw, wacc, 0, 0, 0);
        }
        // modulate IN PLACE: read x(n,c), write M(n,c) at the same LDS address.
        // (n,c) blocks are disjoint across waves (nw x cw partition) -> race-free.
#pragma unroll
        for (int r = 0; r < 16; ++r) {
            int   n   = 32 * nw + (r & 3) + 8 * (r >> 2) + w5_4;
            float cn  = C_s[n];
            int   a   = n * FF + (((c_hi ^ (n & 7)) << 3) | c_lo);
            float xv  = __uint_as_float((unsigned)((const unsigned short*)X_s)[a] << 16);
            X_s[a] = f2bf_fast(wacc[r] * cn * xv);
        }
    }
    __syncthreads();   // M (in X_s) ready

    // ---------------- phase 2: 16x16x32 k/v tiles + max-free softmax + msg ----------
    // Wave w owns head-tile cg = w: bkh/bvh pre-loaded once (4+4 frags);
    // loop body VERBATIM R25/R28, single ct.
    float sums = 0.0f, accs = 0.0f;
    bf16x8 bkh[4], bvh[4];
#pragma unroll
    for (int s = 0; s < 4; ++s) {
        bkh[s] = *(const bf16x8*)&WkB[((w * 4 + s) * 64 + lane) * 8];
        bvh[s] = *(const bf16x8*)&WvB[((w * 4 + s) * 64 + lane) * 8];
    }
#pragma unroll
    for (int mtl = 0; mtl < 4; ++mtl) {
        bf16x8 A[4];
#pragma unroll
        for (int s = 0; s < 4; ++s) {
            int row = 16 * mtl + l15;
            int chunk = (4 * s + quad) ^ (row & 7);
            A[s] = *(const bf16x8*)&X_s[row * FF + chunk * 8];
        }
        f32x4 kacc = {0.f, 0.f, 0.f, 0.f};
#pragma unroll
        for (int s = 0; s < 4; ++s)
            kacc = __builtin_amdgcn_mfma_f32_16x16x32_bf16(A[s], bkh[s], kacc, 0, 0, 0);
        float e[4];
#pragma unroll
        for (int r = 0; r < 4; ++r) {
            float sr = row16_sum(kacc[r] * qs);       // score for (n, head w)
            int   n  = 16 * mtl + quad * 4 + r;
            e[r] = ((mask64 >> n) & 1ull) ? __expf(sr) : 0.0f;
            sums += e[r];
        }
        f32x4 vacc = {0.f, 0.f, 0.f, 0.f};
#pragma unroll
        for (int s = 0; s < 4; ++s)
            vacc = __builtin_amdgcn_mfma_f32_16x16x32_bf16(A[s], bvh[s], vacc, 0, 0, 0);
#pragma unroll
        for (int r = 0; r < 4; ++r) accs = fmaf(e[r], vacc[r], accs);
    }
    // reduce the neighbor partition across quads (lanes differing in bits 4,5)
    sums += __shfl_xor(sums, 16, 64);
    sums += __shfl_xor(sums, 32, 64);
    accs += __shfl_xor(accs, 16, 64);
    accs += __shfl_xor(accs, 32, 64);
    if (quad == 0) {
        msg_bf[16 * w + l15] = f2bf_fast(accs / sums);
    }
    __syncthreads();   // msg_bf ready

    // ---------------- phase 3: out = msg.Wo + x + bo (16x16x32, broadcast-A) --------
    {
        bf16x8 mga[4];
#pragma unroll
        for (int s = 0; s < 4; ++s)
            mga[s] = *(const bf16x8*)&msg_bf[s * 32 + quad * 8];
        f32x4 z = {0.f, 0.f, 0.f, 0.f};
#pragma unroll
        for (int s = 0; s < 4; ++s) {
            bf16x8 bw = *(const bf16x8*)&WoB[((w * 4 + s) * 64 + lane) * 8];
            z = __builtin_amdgcn_mfma_f32_16x16x32_bf16(mga[s], bw, z, 0, 0, 0);
        }
        if (quad == 0) {
            int col = w * 16 + l15;
            out[bao * FF + col] = z[0] + xrow[col] + bo[col];
        }
    }
}

extern "C" void kernel_launch(void* const* d_in, const int* in_sizes, int n_in,
                              void* d_out, int out_size, void* d_ws, size_t ws_size,
                              hipStream_t stream) {
    // 0:e 1:x 2:t 3:r_ij 4:f_ij 5:W_filt 6:b_filt 7:Wq 8:Wk 9:Wv 10:Wo 11:bo
    // 12:neighbors 13:neighbor_mask (bool -> int32)
    const float* x      = (const float*)d_in[1];
    const float* r_ij   = (const float*)d_in[3];
    const float* f_ij   = (const float*)d_in[4];
    const float* W_filt = (const float*)d_in[5];
    const float* b_filt = (const float*)d_in[6];
    const float* Wq     = (const float*)d_in[7];
    const float* Wk     = (const float*)d_in[8];
    const float* Wv     = (const float*)d_in[9];
    const float* Wo     = (const float*)d_in[10];
    const float* bo     = (const float*)d_in[11];
    const int*   nbr    = (const int*)d_in[12];
    const int*   msk    = (const int*)d_in[13];
    float* out = (float*)d_out;

    short* ws  = (short*)d_ws;   // 73728 + 524288 bf16 = 1.17 MB scratch
    short* WkB = ws;
    short* WvB = ws + WKV_ELEMS;
    short* WqB = ws + 2 * WKV_ELEMS;
    short* WoB = ws + 2 * WKV_ELEMS + WQO_ELEMS;
    short* WfB = ws + 2 * WKV_ELEMS + 2 * WQO_ELEMS;
    short* xB  = ws + 2 * WKV_ELEMS + 2 * WQO_ELEMS + WF_ELEMS;

    int prep_total = 2 * WKV_ELEMS + 2 * WQO_ELEMS + WF_ELEMS + XB_ELEMS; // 598016 = 2336*256
    hipLaunchKernelGGL(prep_kernel, dim3(prep_total / 256), dim3(256), 0, stream,
                       Wk, Wv, Wq, Wo, W_filt, b_filt, x, ws);
    hipLaunchKernelGGL(tdt_main, dim3(BB * AA), dim3(512), 0, stream,
                       x, r_ij, f_ij, bo, nbr, msk,
                       WkB, WvB, WqB, WoB, WfB, xB, out);
}

// Round 16
// 145.074 us; speedup vs baseline: 1.0945x; 1.0945x over previous
//
#include <hip/hip_runtime.h>
#include <math.h>

// Problem constants (match reference)
#define BB 8
#define AA 512
#define NBH 64
#define FF 128
#define GG 50
#define CUTOFF 5.0f

typedef __attribute__((ext_vector_type(8)))  short bf16x8;   // 8 bf16 = 4 VGPRs
typedef __attribute__((ext_vector_type(4)))  float f32x4;    // 16x16 MFMA C/D
typedef __attribute__((ext_vector_type(16))) float f32x16;   // 32x32 MFMA C/D

// Packed weight sizes (bf16 elems)
#define WKV_ELEMS (4*8*64*8)   // 16384 : Wk/Wv, 16-col B-frag layout, K=128 (4 steps of 32)
#define WQO_ELEMS (8*4*64*8)   // 16384 : Wq/Wo, 16-col B-frag layout, K=128 (4 steps of 32)
#define WF_ELEMS  (4*4*64*8)   // 8192  : W_filt, 32-col layout, K=64 pad; row 50 = b_filt
#define XB_ELEMS  (BB*AA*FF)   // 524288: x pre-converted to bf16

// RNE (prep only — off critical path)
__device__ __forceinline__ short f2bf(float f) {
    union { float f; unsigned u; } v; v.f = f;
    unsigned r = v.u + 0x7fffu + ((v.u >> 16) & 1u);
    return (short)(r >> 16);
}
// fast round-half-up (2 VALU)
__device__ __forceinline__ short f2bf_fast(float f) {
    return (short)((__float_as_uint(f) + 0x8000u) >> 16);
}
// pack 2 floats -> 2 bf16 in one dword: 2 adds + 1 v_perm
__device__ __forceinline__ unsigned int pk2bf(float a, float b) {
    unsigned int ua = __float_as_uint(a) + 0x8000u;
    unsigned int ub = __float_as_uint(b) + 0x8000u;
    return __builtin_amdgcn_perm(ub, ua, 0x07060302u);
}
// Load 8 consecutive floats (8B-aligned) -> bf16x8 A-fragment (packed cvt).
// Works for LDS-resident sources too (generic pointer -> ds_read_b64).
__device__ __forceinline__ bf16x8 ld_f8_bfpk(const float* p) {
    const float2* p2 = (const float2*)p;
    float2 a = p2[0], b = p2[1], c = p2[2], d = p2[3];
    union { unsigned int u[4]; bf16x8 v; } r;
    r.u[0] = pk2bf(a.x, a.y);
    r.u[1] = pk2bf(b.x, b.y);
    r.u[2] = pk2bf(c.x, c.y);
    r.u[3] = pk2bf(d.x, d.y);
    return r.v;
}

// Sum over the 16-lane DPP row (VALU pipe). All 16 lanes get the sum.
__device__ __forceinline__ float row16_sum(float x) {
    int t;
    t = __builtin_amdgcn_update_dpp(0, __float_as_int(x), 0x128, 0xf, 0xf, true); x += __int_as_float(t); // row_ror:8
    t = __builtin_amdgcn_update_dpp(0, __float_as_int(x), 0x124, 0xf, 0xf, true); x += __int_as_float(t); // row_ror:4
    t = __builtin_amdgcn_update_dpp(0, __float_as_int(x), 0x122, 0xf, 0xf, true); x += __int_as_float(t); // row_ror:2
    t = __builtin_amdgcn_update_dpp(0, __float_as_int(x), 0x121, 0xf, 0xf, true); x += __int_as_float(t); // row_ror:1
    return x;
}

// ---------------- prep: pack weights into MFMA B-fragment order + x -> bf16 ---------
// 16-col layout (Wk/Wv/Wq/Wo): dst[((c*4+s)*64+l)*8+j] = W[32s + (l>>4)*8 + j][16c + (l&15)]
// 32-col layout (Wf):          dst[((w*S+s)*64+l)*8+j] = W[16s + (l>>5)*8 + j][32w + (l&31)]
// Wf K-pad rows 50..63: row 50 carries b_filt (A supplies 1.0 there), 51..63 zero.
__global__ void prep_kernel(const float* __restrict__ Wk,
                            const float* __restrict__ Wv,
                            const float* __restrict__ Wq,
                            const float* __restrict__ Wo,
                            const float* __restrict__ Wf,
                            const float* __restrict__ b_filt,
                            const float* __restrict__ x,
                            short* __restrict__ ws)
{
    int gid = blockIdx.x * blockDim.x + threadIdx.x;
    if (gid < 2 * WKV_ELEMS + 2 * WQO_ELEMS) {
        const float* src = (gid < WKV_ELEMS) ? Wk :
                           (gid < 2 * WKV_ELEMS) ? Wv :
                           (gid < 2 * WKV_ELEMS + WQO_ELEMS) ? Wq : Wo;
        int idx = gid & (WKV_ELEMS - 1);   // all four regions are 16384
        int j = idx & 7, l = (idx >> 3) & 63, rest = idx >> 9;
        int s = rest & 3, c = rest >> 2;
        int k = 32 * s + ((l >> 4) << 3) + j;
        int n = 16 * c + (l & 15);
        ws[gid] = f2bf(src[k * FF + n]);
    } else if (gid < 2 * WKV_ELEMS + 2 * WQO_ELEMS + WF_ELEMS) {
        int idx = gid - 2 * WKV_ELEMS - 2 * WQO_ELEMS;
        int j = idx & 7, l = (idx >> 3) & 63, rest = idx >> 9;
        int s = rest & 3, w = rest >> 2;
        int k = 16 * s + ((l >> 5) << 3) + j;
        int n = 32 * w + (l & 31);
        float v = (k < GG) ? Wf[k * FF + n] : (k == GG ? b_filt[n] : 0.0f);
        ws[gid] = f2bf(v);
    } else {
        int idx = gid - 2 * WKV_ELEMS - 2 * WQO_ELEMS - WF_ELEMS;
        ws[gid] = f2bf(x[idx]);            // xB: straight layout, (b*AA+a)*FF + col
    }
}

// ---------------- main: one block per atom, 4 waves, 3 barriers ----------------
// R32 = R28 (best passing build, main 53.5us / total 145.5) + pre-barrier
// weight-load hoisting. R31's 8-wave split REGRESSED (53.5->67us: no
// occupancy gain, 2x barrier coupling, half the per-wave ILP) — both
// 512-thread geometries (R20, R31) failed; 256/4-wave is the measured
// optimum. Remaining profile: VALU 46.5 + MFMA 18.8 = 65% busy, ~35% stall;
// the twice-confirmed mechanism (R17, R28) is exposed memory latency. Last
// exposed class: POST-barrier L2 weight loads (bfw, bkh/bvh, WoB, xrow/bo)
// whose ~200-400cy latency serializes with dependent compute. Fix: issue
// them BEFORE the preceding __syncthreads — latency drains during the
// barrier wait, and the barrier is a code-motion fence the compiler cannot
// re-sink loads across (defeats the R25/R26 re-sinking). Pure code motion of
// constant-data loads; FP DAG unchanged; peak VGPR ~100 < 128 cap. Watch:
// VGPR should RISE to ~80-100 (hoists stuck); WRITE_SIZE ~2 MB (else spill).
// History: R28 f_ij->F_s entry staging (+8us, predicted). R27 regressed.
// R24 ct-outer interchange failed correctness — loop nests verbatim. NT
// loads (R23) regressed. R19 X_s in-place + source-side chunk-XOR swizzle
// (chunk ^= n&7), LDS dest linear (gl_lds HW). Max-free softmax; final 1/sum.
// kq-style score precompute regressed on TOTALS three ways (R8/R10/R14-16).
__global__ __launch_bounds__(256, 4)
void tdt_main(const float* __restrict__ x,
              const float* __restrict__ r_ij,
              const float* __restrict__ f_ij,
              const float* __restrict__ bo,
              const int*   __restrict__ neighbors,
              const int*   __restrict__ nmask,
              const short* __restrict__ WkB,
              const short* __restrict__ WvB,
              const short* __restrict__ WqB,
              const short* __restrict__ WoB,
              const short* __restrict__ WfB,
              const short* __restrict__ xB,
              float* __restrict__ out)
{
    const int ba   = blockIdx.x;          // 0..4095
    const int b    = ba >> 9;
    const int tid  = threadIdx.x;
    const int lane = tid & 63;
    const int w    = tid >> 6;            // wave 0..3
    const int l15  = lane & 15;
    const int quad = lane >> 4;
    const int l31  = lane & 31;
    const int khalf = (lane >> 5) << 3;   // 0 or 8
    const int w5_4  = (lane >> 5) * 4;

    __shared__ short X_s[NBH * FF];       // gathered x rows, then (in-place) M (16 KB)
    __shared__ __attribute__((aligned(16))) float F_s[NBH * GG];  // f_ij slab (12.8 KB)
    __shared__ short msg_bf[FF];
    __shared__ float C_s[NBH];            // cosine cutoff per neighbor

    const float* xrow = x + (size_t)ba * FF;                       // residual (fp32)
    const unsigned short* xbu = (const unsigned short*)xB + (size_t)b * AA * FF;
    const size_t bao = (size_t)ba;

    // ---------------- entry A: stage f_ij slab -> F_s (async, 16B/lane) -------------
    // Slab = 64*50 floats = 800 16B-chunks, contiguous. Wave w, iter j covers
    // chunks [(j*4+w)*64, +64). 12 instructions cover 768; tail: wave 0 loads
    // chunks 736..799 (32-chunk overlap with wave3/j2 writes identical bytes).
    {
        const float* fsrc = f_ij + bao * (size_t)(NBH * GG);
#pragma unroll
        for (int j = 0; j < 3; ++j) {
            int cbase = (j * 4 + w) * 64;
            __builtin_amdgcn_global_load_lds(
                (const __attribute__((address_space(1))) void*)(fsrc + (size_t)(cbase + lane) * 4),
                (__attribute__((address_space(3))) void*)&F_s[cbase * 4],
                16, 0, 0);
        }
        if (w == 0) {
            __builtin_amdgcn_global_load_lds(
                (const __attribute__((address_space(1))) void*)(fsrc + (size_t)(736 + lane) * 4),
                (__attribute__((address_space(3))) void*)&F_s[736 * 4],
                16, 0, 0);
        }
    }

    // ---------------- entry B: issue neighbor-row gather into X_s (async, 16B/lane) -
    // Wave w stages rows [16w, 16w+16): iteration j covers rows 16w+4j..+3.
    // Lane l writes physical chunk (l&15) of row 16w+4j+(l>>4) (HW: uniform base +
    // lane*16B, linear). SOURCE chunk is (l&15)^(row&7) — so physical chunk jj of
    // row n holds global chunk jj^(n&7): the 16B-chunk XOR swizzle lives in the
    // global address, LDS dest stays linear (global_load_lds requirement).
    {
#pragma unroll
        for (int j = 0; j < 4; ++j) {
            int row = 16 * w + 4 * j + (lane >> 4);
            int nbn = neighbors[bao * NBH + row];
            int kk  = (lane & 15) ^ (row & 7);
            const unsigned short* src = xbu + (size_t)nbn * FF + (size_t)(kk * 8);
            __builtin_amdgcn_global_load_lds(
                (const __attribute__((address_space(1))) void*)src,
                (__attribute__((address_space(3))) void*)&X_s[(16 * w + 4 * j) * FF],
                16, 0, 0);
        }
    }

    // cutoff envelope -> C_s (wave 0 only; published by the phase-1a barrier)
    if (w == 0) {
        float r = r_ij[bao * NBH + lane];
        float c = 0.5f * (__cosf((float)M_PI * r * (1.0f / CUTOFF)) + 1.0f);
        C_s[lane] = (r < CUTOFF) ? c : 0.0f;
    }
    unsigned long long mask64 = __ballot(nmask[bao * NBH + lane] != 0);

    // R32: phase-3 residual/bias preloaded at entry (constant data, tiny)
    float xr_pre[2], bo_pre[2];
#pragma unroll
    for (int ct = 0; ct < 2; ++ct) {
        int col = (2 * w + ct) * 16 + l15;
        xr_pre[ct] = xrow[col];
        bo_pre[ct] = bo[col];
    }

    // ---------------- phase 1a: q via 16x16x32 MFMA (broadcast-A from xB) -----------
    // qs[ct] = 0.25 * q[16*(2w+ct) + l15] — one q value per head-tile, all quads.
    float qs[2];
    {
        const short* xbrow = &xB[(size_t)ba * FF];
        bf16x8 xa[4];
#pragma unroll
        for (int s = 0; s < 4; ++s)
            xa[s] = *(const bf16x8*)&xbrow[32 * s + quad * 8];     // raw 16B, no cvt
#pragma unroll
        for (int ct = 0; ct < 2; ++ct) {
            int cg = 2 * w + ct;
            f32x4 z = {0.f, 0.f, 0.f, 0.f};
#pragma unroll
            for (int s = 0; s < 4; ++s) {
                bf16x8 bq = *(const bf16x8*)&WqB[((cg * 4 + s) * 64 + lane) * 8];
                z = __builtin_amdgcn_mfma_f32_16x16x32_bf16(xa[s], bq, z, 0, 0, 0);
            }
            qs[ct] = z[0] * 0.25f;                                 // fold 1/sqrt(DH)
        }
    }

    // R32: hoist mt-invariant WfB frags ABOVE barrier 1 — L2 latency drains
    // during the barrier wait; the barrier pins them (no re-sink, cf. R25/R26).
    bf16x8 bfw[4];
#pragma unroll
    for (int s = 0; s < 4; ++s)
        bfw[s] = *(const bf16x8*)&WfB[((w * 4 + s) * 64 + lane) * 8];

    __syncthreads();   // X_s + F_s + C_s ready (syncthreads drains vmcnt incl. gl_lds)

    // ---------------- phase 1b: filter 32x32x16 MFMA (A from LDS F_s), mt-split -----
    {
        const float* fm0 = F_s + (size_t)l31 * GG;                 // LDS now, not global
        const int c_hi = 4 * w + (l31 >> 3);   // c>>3 of this lane's column
        const int c_lo = l31 & 7;              // c&7
#pragma unroll
        for (int mt = 0; mt < 2; ++mt) {
            f32x16 wacc;
#pragma unroll
            for (int r = 0; r < 16; ++r) wacc[r] = 0.0f;
            const float* fm = fm0 + mt * 32 * GG;
#pragma unroll
            for (int s = 0; s < 4; ++s) {
                bf16x8 fa;
                if (s < 3) {
                    fa = ld_f8_bfpk(fm + 16 * s + khalf);
                } else {
                    // k = 48 + khalf + j; k<50 real data, k==50 bias row (A=1.0)
#pragma unroll
                    for (int jj = 0; jj < 8; ++jj) fa[jj] = 0;
                    if (lane < 32) {
                        fa[0] = f2bf_fast(fm[48]);
                        fa[1] = f2bf_fast(fm[49]);
                        fa[2] = (short)0x3F80;   // 1.0bf16 -> adds b_filt row
                    }
                }
                wacc = __builtin_amdgcn_mfma_f32_32x32x16_bf16(fa, bfw[s], wacc, 0, 0, 0);
            }
            // modulate IN PLACE: read x(n,c), write M(n,c) at the same LDS address.
            // Each (n,c) element is owned by exactly one lane -> race-free.
#pragma unroll
            for (int r = 0; r < 16; ++r) {
                int   n   = 32 * mt + (r & 3) + 8 * (r >> 2) + w5_4;
                float cn  = C_s[n];
                int   a   = n * FF + (((c_hi ^ (n & 7)) << 3) | c_lo);
                float xv  = __uint_as_float((unsigned)((const unsigned short*)X_s)[a] << 16);
                X_s[a] = f2bf_fast(wacc[r] * cn * xv);
            }
        }
    }

    // R32: hoist phase-2 weight frags ABOVE barrier 2 (same trick; bfw now dead)
    bf16x8 bkh[2][4], bvh[2][4];
#pragma unroll
    for (int ct = 0; ct < 2; ++ct) {
        int cg = 2 * w + ct;
#pragma unroll
        for (int s = 0; s < 4; ++s) {
            bkh[ct][s] = *(const bf16x8*)&WkB[((cg * 4 + s) * 64 + lane) * 8];
            bvh[ct][s] = *(const bf16x8*)&WvB[((cg * 4 + s) * 64 + lane) * 8];
        }
    }

    __syncthreads();   // M (in X_s) ready

    // ---------------- phase 2: 16x16x32 k/v tiles + max-free softmax + msg ----------
    // Loop nest VERBATIM R22/R25/R28 (mtl outer, ct inner); bkh/bvh preloaded.
    float sums[2] = {0.0f, 0.0f}, accs[2] = {0.0f, 0.0f};
#pragma unroll
    for (int mtl = 0; mtl < 4; ++mtl) {
        bf16x8 A[4];
#pragma unroll
        for (int s = 0; s < 4; ++s) {
            int row = 16 * mtl + l15;
            int chunk = (4 * s + quad) ^ (row & 7);
            A[s] = *(const bf16x8*)&X_s[row * FF + chunk * 8];
        }
#pragma unroll
        for (int ct = 0; ct < 2; ++ct) {
            f32x4 kacc = {0.f, 0.f, 0.f, 0.f};
#pragma unroll
            for (int s = 0; s < 4; ++s)
                kacc = __builtin_amdgcn_mfma_f32_16x16x32_bf16(A[s], bkh[ct][s], kacc, 0, 0, 0);
            float e[4];
#pragma unroll
            for (int r = 0; r < 4; ++r) {
                float sr = row16_sum(kacc[r] * qs[ct]);   // score for (n, head cg)
                int   n  = 16 * mtl + quad * 4 + r;
                e[r] = ((mask64 >> n) & 1ull) ? __expf(sr) : 0.0f;
                sums[ct] += e[r];
            }
            f32x4 vacc = {0.f, 0.f, 0.f, 0.f};
#pragma unroll
            for (int s = 0; s < 4; ++s)
                vacc = __builtin_amdgcn_mfma_f32_16x16x32_bf16(A[s], bvh[ct][s], vacc, 0, 0, 0);
#pragma unroll
            for (int r = 0; r < 4; ++r) accs[ct] = fmaf(e[r], vacc[r], accs[ct]);
        }
    }
    // reduce the neighbor partition across quads (lanes differing in bits 4,5)
#pragma unroll
    for (int ct = 0; ct < 2; ++ct) {
        sums[ct] += __shfl_xor(sums[ct], 16, 64);
        sums[ct] += __shfl_xor(sums[ct], 32, 64);
        accs[ct] += __shfl_xor(accs[ct], 16, 64);
        accs[ct] += __shfl_xor(accs[ct], 32, 64);
    }
    if (quad == 0) {
        msg_bf[16 * (2 * w + 0) + l15] = f2bf_fast(accs[0] / sums[0]);
        msg_bf[16 * (2 * w + 1) + l15] = f2bf_fast(accs[1] / sums[1]);
    }

    // R32: hoist phase-3 WoB frags ABOVE barrier 3 (accs/sums/bkh/bvh now dead)
    bf16x8 bwo[2][4];
#pragma unroll
    for (int ct = 0; ct < 2; ++ct) {
        int cg = 2 * w + ct;
#pragma unroll
        for (int s = 0; s < 4; ++s)
            bwo[ct][s] = *(const bf16x8*)&WoB[((cg * 4 + s) * 64 + lane) * 8];
    }

    __syncthreads();   // msg_bf ready

    // ---------------- phase 3: out = msg.Wo + x + bo (16x16x32, broadcast-A) --------
    {
        bf16x8 mga[4];
#pragma unroll
        for (int s = 0; s < 4; ++s)
            mga[s] = *(const bf16x8*)&msg_bf[s * 32 + quad * 8];
#pragma unroll
        for (int ct = 0; ct < 2; ++ct) {
            f32x4 z = {0.f, 0.f, 0.f, 0.f};
#pragma unroll
            for (int s = 0; s < 4; ++s)
                z = __builtin_amdgcn_mfma_f32_16x16x32_bf16(mga[s], bwo[ct][s], z, 0, 0, 0);
            if (quad == 0) {
                int col = (2 * w + ct) * 16 + l15;
                out[bao * FF + col] = z[0] + xr_pre[ct] + bo_pre[ct];
            }
        }
    }
}

extern "C" void kernel_launch(void* const* d_in, const int* in_sizes, int n_in,
                              void* d_out, int out_size, void* d_ws, size_t ws_size,
                              hipStream_t stream) {
    // 0:e 1:x 2:t 3:r_ij 4:f_ij 5:W_filt 6:b_filt 7:Wq 8:Wk 9:Wv 10:Wo 11:bo
    // 12:neighbors 13:neighbor_mask (bool -> int32)
    const float* x      = (const float*)d_in[1];
    const float* r_ij   = (const float*)d_in[3];
    const float* f_ij   = (const float*)d_in[4];
    const float* W_filt = (const float*)d_in[5];
    const float* b_filt = (const float*)d_in[6];
    const float* Wq     = (const float*)d_in[7];
    const float* Wk     = (const float*)d_in[8];
    const float* Wv     = (const float*)d_in[9];
    const float* Wo     = (const float*)d_in[10];
    const float* bo     = (const float*)d_in[11];
    const int*   nbr    = (const int*)d_in[12];
    const int*   msk    = (const int*)d_in[13];
    float* out = (float*)d_out;

    short* ws  = (short*)d_ws;   // 73728 + 524288 bf16 = 1.17 MB scratch
    short* WkB = ws;
    short* WvB = ws + WKV_ELEMS;
    short* WqB = ws + 2 * WKV_ELEMS;
    short* WoB = ws + 2 * WKV_ELEMS + WQO_ELEMS;
    short* WfB = ws + 2 * WKV_ELEMS + 2 * WQO_ELEMS;
    short* xB  = ws + 2 * WKV_ELEMS + 2 * WQO_ELEMS + WF_ELEMS;

    int prep_total = 2 * WKV_ELEMS + 2 * WQO_ELEMS + WF_ELEMS + XB_ELEMS; // 598016 = 2336*256
    hipLaunchKernelGGL(prep_kernel, dim3(prep_total / 256), dim3(256), 0, stream,
                       Wk, Wv, Wq, Wo, W_filt, b_filt, x, ws);
    hipLaunchKernelGGL(tdt_main, dim3(BB * AA), dim3(256), 0, stream,
                       x, r_ij, f_ij, bo, nbr, msk,
                       WkB, WvB, WqB, WoB, WfB, xB, out);
}